// Round 10
// baseline (165.973 us; speedup 1.0000x reference)
//
#include <hip/hip_runtime.h>
#include <hip/hip_fp16.h>

typedef __attribute__((ext_vector_type(8))) short short8;
typedef __attribute__((ext_vector_type(4))) float f32x4;
typedef unsigned short ushort_t;
typedef unsigned int uint_t;

#define B_SZ 32
#define T_SZ 4096
#define D_IN 256
#define H_SZ 256
#define M_SZ (B_SZ * T_SZ)  // 131072
#define CHUNK 64
#define NCHUNK (T_SZ / CHUNK)  // 64

__device__ __forceinline__ ushort_t f2bf(float f) {
  unsigned int u = __float_as_uint(f);
  unsigned int r = (u + 0x7FFFu + ((u >> 16) & 1u)) >> 16;
  return (ushort_t)r;
}

__device__ __forceinline__ float sigmoidf_(float xv) {
  float e = __expf(-fabsf(xv));
  float s = 1.0f / (1.0f + e);
  return xv >= 0.0f ? s : 1.0f - s;
}

__device__ __forceinline__ float unpack_lo(uint_t pk) {
  return __half2float(__ushort_as_half((ushort_t)(pk & 0xFFFFu)));
}
__device__ __forceinline__ float unpack_hi(uint_t pk) {
  return __half2float(__ushort_as_half((ushort_t)(pk >> 16)));
}

// ---------------------------------------------------------------------------
// Kernel 1 (unchanged): pack W'' (Wz,Wh interleaved by 16-col groups) into
// bf16, GRANULE-MAJOR per kstep: granule = c*512 + n.
// ---------------------------------------------------------------------------
__global__ void prep_w(const float* __restrict__ Wz, const float* __restrict__ Wh,
                       ushort_t* __restrict__ wsB) {
  int g = blockIdx.x * 256 + threadIdx.x;  // 16384 granules total
  if (g >= 8 * 2048) return;
  int ks = g >> 11;
  int r = g & 2047;
  int c = r >> 9;        // 0..3
  int n = r & 511;       // 0..511
  int h = (n >> 5) * 16 + (n & 15);
  const float* W = ((n >> 4) & 1) ? Wh : Wz;
  const float* src = W + (size_t)h * D_IN + ks * 32 + c * 8;
  ushort_t* dst = wsB + (size_t)g * 8;
#pragma unroll
  for (int j = 0; j < 8; ++j) dst[j] = f2bf(src[j]);
}

// ---------------------------------------------------------------------------
// Kernel 2: r9 GEMM with ONE change — A-staging batched: all 512 threads,
// thread t owns granule g=t>>1 half t&1 (row=g&63, c=g>>6), and ALL 8 ksteps'
// x float4 loads are issued in the prologue into pf[8] (32 VGPR). They drain
// ONCE at barrier 0; barriers 1..7 only drain B's L2-resident gload_lds.
// Per kstep the A write-late converts from resident registers (zero vm wait).
// LDS image identical to r9 (granule = c*64+row, 16B). Epilogue = r9 verbatim
// (gate math + packed av + fused chunk-affine reduce -> cAV).
// ---------------------------------------------------------------------------
__global__ __launch_bounds__(512, 4) void gemm_av(
    const float* __restrict__ x, const ushort_t* __restrict__ wsB,
    const float* __restrict__ bz, const float* __restrict__ bh,
    uint_t* __restrict__ av, float2* cAV) {
  __shared__ __align__(16) unsigned char lds[73728];
  ushort_t* As = (ushort_t*)lds;                  // 2 x 4096 B  (2048 el/buf)
  ushort_t* Bs = (ushort_t*)(lds + 8192);         // 2 x 32768 B (16384 el/buf)

  const int tid = threadIdx.x;
  const int lane = tid & 63;
  const int wid = tid >> 6;         // 0..7 = N-group
  const int m0 = blockIdx.x * 64;

  // A-stage mapping (ALL 512 threads): granule g = tid>>1, half = tid&1.
  // Granule content (16B): bf16 x[m0 + (g&63)][ks*32 + (g>>6)*8 .. +7].
  const int a_row = (tid >> 1) & 63;
  const int a_c = tid >> 7;        // 0..3
  const int a_half = tid & 1;      // which float4 of the granule
  const float* asrc = x + (size_t)(m0 + a_row) * D_IN + a_c * 8 + a_half * 4;

  // ---- batched A prefetch: all 8 ksteps issued up front ----
  float4 pf[8];
#pragma unroll
  for (int ks = 0; ks < 8; ++ks) pf[ks] = *(const float4*)(asrc + ks * 32);

  f32x4 acc[4][4];
#pragma unroll
  for (int rt = 0; rt < 4; ++rt)
#pragma unroll
    for (int ct = 0; ct < 4; ++ct) {
      f32x4 z4 = {0.f, 0.f, 0.f, 0.f};
      acc[rt][ct] = z4;
    }

  // ---- prologue: stage kstep 0 into buffer 0 ----
  {
    const ushort_t* bsrc = wsB + (size_t)wid * 2048 + lane * 8;
    ushort_t* bdst = Bs + wid * 2048;
#pragma unroll
    for (int cc = 0; cc < 4; ++cc) {
      __builtin_amdgcn_global_load_lds(
          (const __attribute__((address_space(1))) void*)(bsrc + cc * 512),
          (__attribute__((address_space(3))) void*)(bdst + cc * 512), 16, 0, 0);
    }
    uint2 w;
    w.x = (uint_t)f2bf(pf[0].x) | ((uint_t)f2bf(pf[0].y) << 16);
    w.y = (uint_t)f2bf(pf[0].z) | ((uint_t)f2bf(pf[0].w) << 16);
    *(uint2*)((char*)As + tid * 8) = w;
  }
  __syncthreads();

#pragma unroll
  for (int ks = 0; ks < 8; ++ks) {
    const int cur = ks & 1;
    // 1. LDS -> register fragments (granule-major: granule = c*NROWS + idx)
    short8 afr[4], bfr[4];
    {
      const int c = lane >> 4;
      const int r16 = lane & 15;
#pragma unroll
      for (int rt = 0; rt < 4; ++rt) {
        int row = rt * 16 + r16;
        afr[rt] = *(const short8*)(As + cur * 2048 + (c * 64 + row) * 8);
      }
#pragma unroll
      for (int ct = 0; ct < 4; ++ct) {
        int n = wid * 64 + ct * 16 + r16;
        bfr[ct] = *(const short8*)(Bs + cur * 16384 + (c * 512 + n) * 8);
      }
    }
    // 2. issue next-kstep B staging (latency hides under MFMAs)
    if (ks < 7) {
      const ushort_t* bsrc = wsB + (size_t)(ks + 1) * 16384 + wid * 2048 + lane * 8;
      ushort_t* bdst = Bs + (cur ^ 1) * 16384 + wid * 2048;
#pragma unroll
      for (int cc = 0; cc < 4; ++cc) {
        __builtin_amdgcn_global_load_lds(
            (const __attribute__((address_space(1))) void*)(bsrc + cc * 512),
            (__attribute__((address_space(3))) void*)(bdst + cc * 512), 16, 0, 0);
      }
    }
    // 3. MFMAs
#pragma unroll
    for (int rt = 0; rt < 4; ++rt)
#pragma unroll
      for (int ct = 0; ct < 4; ++ct)
        acc[rt][ct] = __builtin_amdgcn_mfma_f32_16x16x32_bf16(
            afr[rt], bfr[ct], acc[rt][ct], 0, 0, 0);
    // 4. A write-late from RESIDENT registers (no vm wait; pf index static)
    if (ks < 7) {
      uint2 w;
      w.x = (uint_t)f2bf(pf[ks + 1].x) | ((uint_t)f2bf(pf[ks + 1].y) << 16);
      w.y = (uint_t)f2bf(pf[ks + 1].z) | ((uint_t)f2bf(pf[ks + 1].w) << 16);
      *(uint2*)((char*)As + (cur ^ 1) * 4096 + tid * 8) = w;
    }
    __syncthreads();
  }

  // ---- epilogue (r9 verbatim): gate math + av + fused chunk-affine reduce ----
  const int col16 = lane & 15;
  const int rgrp = lane >> 4;
#pragma unroll
  for (int i = 0; i < 2; ++i) {
    int hh = (wid * 2 + i) * 16 + col16;
    float bzv = bz[hh];
    float bhv = bh[hh];
    float CA = 1.0f, CV = 0.0f;   // running compose over rt windows
#pragma unroll
    for (int rt = 0; rt < 4; ++rt) {
      float A4 = 1.0f, V4 = 0.0f; // this thread's 4 rows (ascending j = time)
#pragma unroll
      for (int j = 0; j < 4; ++j) {
        int row = m0 + rt * 16 + rgrp * 4 + j;
        float kv = acc[rt][2 * i][j] + bzv;
        float pv = acc[rt][2 * i + 1][j] + bhv;
        float a = sigmoidf_(-kv);       // 1 - sigmoid(k)
        float z = 1.0f - a;             // sigmoid(k)
        float gg = (pv >= 0.0f) ? (pv + 0.5f) : sigmoidf_(pv);
        float vv = z * gg;
        uint_t pk = (uint_t)__half_as_ushort(__float2half_rn(a)) |
                    ((uint_t)__half_as_ushort(__float2half_rn(vv)) << 16);
        av[(size_t)row * H_SZ + hh] = pk;
        V4 = fmaf(a, V4, vv);
        A4 *= a;
      }
      // butterfly compose across rgrp (time order)
      float Ap = __shfl_xor(A4, 16);
      float Vp = __shfl_xor(V4, 16);
      float A8 = A4 * Ap;
      float V8 = (lane & 16) ? fmaf(A4, Vp, V4) : fmaf(Ap, V4, Vp);
      float Ap2 = __shfl_xor(A8, 32);
      float Vp2 = __shfl_xor(V8, 32);
      float A16 = A8 * Ap2;
      float V16 = (lane & 32) ? fmaf(A8, Vp2, V8) : fmaf(Ap2, V8, Vp2);
      // rt windows ascend in time
      CV = fmaf(A16, CV, V16);
      CA = CA * A16;
    }
    if (cAV != nullptr && lane < 16) {
      float2 r; r.x = CA; r.y = CV;
      cAV[(size_t)blockIdx.x * H_SZ + hh] = r;  // chunkIdx == blockIdx.x
    }
  }
}

// ---------------------------------------------------------------------------
// Phase 2 (unchanged): per (b,h) sequentially compose chunk summaries from
// g(h0), writing the INCOMING h for each chunk. 32 blocks x 256 thr.
// ---------------------------------------------------------------------------
__global__ __launch_bounds__(256) void chunk_carry(
    const float* __restrict__ h0, const float2* __restrict__ cAV,
    float* __restrict__ hb) {
  const int b = blockIdx.x;
  const int h = threadIdx.x;
  float v0 = h0[b * H_SZ + h];
  float hc = (v0 >= 0.0f) ? (v0 + 0.5f) : sigmoidf_(v0);

  const float2* p = cAV + (size_t)b * NCHUNK * H_SZ + h;
  float* o = hb + (size_t)b * NCHUNK * H_SZ + h;

  float2 buf[NCHUNK];
#pragma unroll
  for (int c = 0; c < NCHUNK; ++c) buf[c] = p[(size_t)c * H_SZ];

#pragma unroll
  for (int c = 0; c < NCHUNK; ++c) {
    o[(size_t)c * H_SZ] = hc;
    hc = fmaf(buf[c].x, hc, buf[c].y);
  }
}

// ---------------------------------------------------------------------------
// Phase 3 (unchanged): per (b, chunk): start from carry, re-scan av, write
// fp32 out. av may alias out (in-place fallback).
// ---------------------------------------------------------------------------
__global__ __launch_bounds__(256) void chunk_scan_out(
    const uint_t* av, const float* __restrict__ hb, float* out) {
  const int b = blockIdx.x >> 6;
  const int c = blockIdx.x & 63;
  const int h = threadIdx.x;

  float hc = hb[((size_t)b * NCHUNK + c) * H_SZ + h];
  const uint_t* p = av + ((size_t)b * T_SZ + c * CHUNK) * H_SZ + h;
  float* o = out + ((size_t)b * T_SZ + c * CHUNK) * H_SZ + h;

  uint_t buf[CHUNK];
#pragma unroll
  for (int s = 0; s < CHUNK; ++s) buf[s] = p[(size_t)s * H_SZ];

#pragma unroll
  for (int s = 0; s < CHUNK; ++s) {
    float a = unpack_lo(buf[s]);
    float v = unpack_hi(buf[s]);
    hc = fmaf(a, hc, v);
    o[(size_t)s * H_SZ] = hc;
  }
}

// Fallback (unchanged): fully-sequential scan.
__global__ __launch_bounds__(64) void scan_seq(const float* __restrict__ h0,
                                               const uint_t* av, float* out) {
  const int b = blockIdx.x >> 2;
  const int hg = blockIdx.x & 3;
  const int h = hg * 64 + threadIdx.x;

  float v0 = h0[b * H_SZ + h];
  float hc = (v0 >= 0.0f) ? (v0 + 0.5f) : sigmoidf_(v0);

  const uint_t* p = av + (size_t)b * T_SZ * H_SZ + h;
  float* o = out + (size_t)b * T_SZ * H_SZ + h;

  uint_t buf[32];
#pragma unroll
  for (int d = 0; d < 32; ++d) buf[d] = p[(size_t)d * H_SZ];

  for (int t0 = 0; t0 < T_SZ; t0 += 32) {
#pragma unroll
    for (int d = 0; d < 32; ++d) {
      int t = t0 + d;
      uint_t pk = buf[d];
      int tn = t + 32;
      if (tn < T_SZ) buf[d] = p[(size_t)tn * H_SZ];
      hc = fmaf(unpack_lo(pk), hc, unpack_hi(pk));
      o[(size_t)t * H_SZ] = hc;
    }
  }
}

extern "C" void kernel_launch(void* const* d_in, const int* in_sizes, int n_in,
                              void* d_out, int out_size, void* d_ws, size_t ws_size,
                              hipStream_t stream) {
  const float* x  = (const float*)d_in[0];
  const float* h0 = (const float*)d_in[1];
  const float* Wz = (const float*)d_in[2];
  const float* bz = (const float*)d_in[3];
  const float* Wh = (const float*)d_in[4];
  const float* bh = (const float*)d_in[5];
  float* out = (float*)d_out;

  // ws layout: [wsB 256K][cAV 4M][hb 2M][pad to 8M][av 134M if it fits]
  const size_t wsBBytes = 262144;
  const size_t cavBytes = (size_t)B_SZ * NCHUNK * H_SZ * 8;   // 4 MiB
  const size_t hbBytes  = (size_t)B_SZ * NCHUNK * H_SZ * 4;   // 2 MiB
  const size_t avOff    = 8388608;
  const size_t avBytes  = (size_t)M_SZ * H_SZ * 4;            // 134 MiB

  ushort_t* wsB = (ushort_t*)d_ws;
  float2* cAV = (float2*)((char*)d_ws + wsBBytes);
  float* hb   = (float*)((char*)d_ws + wsBBytes + cavBytes);

  const bool haveSummaries = ws_size >= wsBBytes + cavBytes + hbBytes;
  uint_t* av;
  if (ws_size >= avOff + avBytes) {
    av = (uint_t*)((char*)d_ws + avOff);
  } else {
    av = (uint_t*)d_out;  // in-place: scan reads av[t] before writing h[t]
  }

  prep_w<<<64, 256, 0, stream>>>(Wz, Wh, wsB);
  gemm_av<<<M_SZ / 64, 512, 0, stream>>>(x, wsB, bz, bh, av,
                                         haveSummaries ? cAV : (float2*)nullptr);
  if (haveSummaries) {
    chunk_carry<<<B_SZ, 256, 0, stream>>>(h0, cAV, hb);
    chunk_scan_out<<<B_SZ * NCHUNK, 256, 0, stream>>>(av, hb, out);
  } else {
    scan_seq<<<B_SZ * 4, 64, 0, stream>>>(h0, av, out);
  }
}